// Round 6
// baseline (360.075 us; speedup 1.0000x reference)
//
#include <hip/hip_runtime.h>
#include <hip/hip_bf16.h>
#include <math.h>

#define D 128
#define LRELU_SLOPE 0.2f
#define BSH 9
#define BSZ 512
#define SC_CHUNK 16384

typedef __attribute__((ext_vector_type(8))) short bf16x8;
typedef __attribute__((ext_vector_type(4))) float f32x4;

__device__ __forceinline__ float lrelu(float x){ return x > 0.f ? x : LRELU_SLOPE * x; }

__device__ __forceinline__ unsigned short bf16_rn(float x){
  unsigned int u = __float_as_uint(x);
  return (unsigned short)((u + 0x7FFFu + ((u >> 16) & 1u)) >> 16);
}
__device__ __forceinline__ float bf16_lo_f(unsigned int u){ return __uint_as_float(u << 16); }
__device__ __forceinline__ float bf16_hi_f(unsigned int u){ return __uint_as_float(u & 0xFFFF0000u); }

// ---------------- bucketed CSR build ----------------
__global__ __launch_bounds__(1024) void bucket_count_kernel(const int* __restrict__ dst, int E,
    int* __restrict__ bcnt, int nbuck){
  __shared__ int h[256];
  int t = threadIdx.x;
  if (t < 256) h[t] = 0;
  __syncthreads();
  for (int e = blockIdx.x*1024 + t; e < E; e += gridDim.x*1024)
    atomicAdd(&h[dst[e] >> BSH], 1);
  __syncthreads();
  if (t < nbuck && h[t]) atomicAdd(&bcnt[t], h[t]);
}

__global__ __launch_bounds__(256) void bucket_scan_kernel(const int* __restrict__ bcnt,
    int* __restrict__ bbase, int* __restrict__ bcur, int nbuck, int E){
  __shared__ int s[256];
  int t = threadIdx.x;
  int v = (t < nbuck) ? bcnt[t] : 0;
  s[t] = v;
  __syncthreads();
  #pragma unroll
  for (int d = 1; d < 256; d <<= 1){
    int add = (t >= d) ? s[t-d] : 0;
    __syncthreads();
    s[t] += add;
    __syncthreads();
  }
  if (t < nbuck){ int b = s[t] - v; bbase[t] = b; bcur[t] = b; }
  if (t == 0) bbase[nbuck] = E;
}

__global__ __launch_bounds__(1024) void bucket_scatter_kernel(const int* __restrict__ src,
    const int* __restrict__ dst, int E, int* __restrict__ bcur,
    unsigned int* __restrict__ ebuf, int nbuck){
  __shared__ int h[256];
  __shared__ int cb[256];
  int t = threadIdx.x;
  int base = blockIdx.x * SC_CHUNK;
  int end = base + SC_CHUNK; if (end > E) end = E;
  if (t < 256) h[t] = 0;
  __syncthreads();
  for (int e = base + t; e < end; e += 1024)
    atomicAdd(&h[dst[e] >> BSH], 1);
  __syncthreads();
  if (t < nbuck){
    cb[t] = h[t] ? atomicAdd(&bcur[t], h[t]) : 0;
    h[t] = 0;
  }
  __syncthreads();
  for (int e = base + t; e < end; e += 1024){
    int d = dst[e];
    int b = d >> BSH;
    int lpos = atomicAdd(&h[b], 1);
    ebuf[cb[b] + lpos] = ((unsigned int)src[e] << BSH) | (unsigned int)(d & (BSZ-1));
  }
}

__global__ __launch_bounds__(256) void bucket_csr_kernel(const unsigned int* __restrict__ ebuf,
    const int* __restrict__ bbase, int* __restrict__ row_ptr, int* __restrict__ col,
    int n, int nbuck){
  __shared__ int c[512];
  __shared__ int ps[256];
  int b = blockIdx.x;
  int t = threadIdx.x;
  int base = bbase[b], end = bbase[b+1];
  c[t] = 0; c[t+256] = 0;
  __syncthreads();
  for (int i = base + t; i < end; i += 256)
    atomicAdd(&c[ebuf[i] & (BSZ-1)], 1);
  __syncthreads();
  int a0 = c[2*t], a1 = c[2*t+1];
  int pair = a0 + a1;
  ps[t] = pair;
  __syncthreads();
  #pragma unroll
  for (int d = 1; d < 256; d <<= 1){
    int add = (t >= d) ? ps[t-d] : 0;
    __syncthreads();
    ps[t] += add;
    __syncthreads();
  }
  int excl = ps[t] - pair;
  __syncthreads();
  int lo = b << BSH;
  int g0 = lo + 2*t, g1 = g0 + 1;
  if (g0 < n) row_ptr[g0] = base + excl;
  if (g1 < n) row_ptr[g1] = base + excl + a0;
  c[2*t]   = excl;
  c[2*t+1] = excl + a0;
  __syncthreads();
  for (int i = base + t; i < end; i += 256){
    unsigned int p = ebuf[i];
    int dlo = p & (BSZ-1);
    int pos = base + atomicAdd(&c[dlo], 1);
    col[pos] = (int)(p >> BSH);
  }
  if (b == 0 && t == 0) row_ptr[n] = bbase[nbuck];
}

// ---------------- W pre-split ----------------
__global__ __launch_bounds__(256) void wsplit_kernel(const float* __restrict__ W,
    unsigned short* __restrict__ Wh, unsigned short* __restrict__ Wl){
  int t = blockIdx.x*256 + threadIdx.x;
  int k  = t >> 7;
  int nn = t & 127;
  float w = W[t];
  unsigned short h = bf16_rn(w);
  float whf = __uint_as_float(((unsigned int)h) << 16);
  unsigned short l = bf16_rn(w - whf);
  int idx = nn*128 + (((k>>3) ^ (nn&7)) << 3) + (k & 7);
  Wh[idx] = h; Wl[idx] = l;
}

// ---------------- MFMA bf16 split-precision GEMM + attention logits ----------------
__global__ __launch_bounds__(256) void gemm_al_kernel(const float* __restrict__ X,
    const unsigned short* __restrict__ Wgh, const unsigned short* __restrict__ Wgl,
    const float* __restrict__ a_src, const float* __restrict__ a_dst,
    unsigned short* __restrict__ Hb, float* __restrict__ ALs, float* __restrict__ ALd, int n)
{
  __shared__ unsigned short Xh[128*128];
  __shared__ unsigned short Xl[128*128];
  __shared__ unsigned short Wh[128*128];
  __shared__ unsigned short Wl[128*128];
  int tid  = threadIdx.x;
  int lane = tid & 63;
  int wave = tid >> 6;
  int row0 = blockIdx.x * 128;

  #pragma unroll
  for (int i = 0; i < 8; ++i){
    int idx = i*256 + tid;
    ((uint4*)Wh)[idx] = ((const uint4*)Wgh)[idx];
    ((uint4*)Wl)[idx] = ((const uint4*)Wgl)[idx];
  }
  #pragma unroll 4
  for (int it = 0; it < 16; ++it){
    int f  = it*256 + tid;
    int r  = f >> 5;
    int c4 = f & 31;
    float4 v = make_float4(0.f,0.f,0.f,0.f);
    int gr = row0 + r;
    if (gr < n) v = ((const float4*)(X + (size_t)gr*D))[c4];
    unsigned short h0 = bf16_rn(v.x);
    unsigned short h1 = bf16_rn(v.y);
    unsigned short h2 = bf16_rn(v.z);
    unsigned short h3 = bf16_rn(v.w);
    unsigned short l0 = bf16_rn(v.x - __uint_as_float(((unsigned)h0)<<16));
    unsigned short l1 = bf16_rn(v.y - __uint_as_float(((unsigned)h1)<<16));
    unsigned short l2 = bf16_rn(v.z - __uint_as_float(((unsigned)h2)<<16));
    unsigned short l3 = bf16_rn(v.w - __uint_as_float(((unsigned)h3)<<16));
    int g   = (c4 >> 1) ^ (r & 7);
    int idx = r*128 + (g << 3) + ((c4 & 1) << 2);
    *(uint2*)&Xh[idx] = make_uint2((unsigned)h0 | ((unsigned)h1<<16),
                                   (unsigned)h2 | ((unsigned)h3<<16));
    *(uint2*)&Xl[idx] = make_uint2((unsigned)l0 | ((unsigned)l1<<16),
                                   (unsigned)l2 | ((unsigned)l3<<16));
  }
  __syncthreads();

  int l15 = lane & 15;
  int l4  = lane >> 4;

  f32x4 acc[2][8];
  #pragma unroll
  for (int rf = 0; rf < 2; ++rf)
    #pragma unroll
    for (int cf = 0; cf < 8; ++cf)
      acc[rf][cf] = (f32x4){0.f, 0.f, 0.f, 0.f};

  #pragma unroll
  for (int kc = 0; kc < 4; ++kc){
    int g = kc*4 + l4;
    bf16x8 ah[2], al[2];
    #pragma unroll
    for (int rf = 0; rf < 2; ++rf){
      int r   = wave*32 + rf*16 + l15;
      int idx = r*128 + ((g ^ (r & 7)) << 3);
      ah[rf] = *(const bf16x8*)&Xh[idx];
      al[rf] = *(const bf16x8*)&Xl[idx];
    }
    #pragma unroll
    for (int cf = 0; cf < 8; ++cf){
      int nn  = cf*16 + l15;
      int idx = nn*128 + ((g ^ (nn & 7)) << 3);
      bf16x8 bh = *(const bf16x8*)&Wh[idx];
      bf16x8 bl = *(const bf16x8*)&Wl[idx];
      #pragma unroll
      for (int rf = 0; rf < 2; ++rf){
        acc[rf][cf] = __builtin_amdgcn_mfma_f32_16x16x32_bf16(ah[rf], bh, acc[rf][cf], 0, 0, 0);
        acc[rf][cf] = __builtin_amdgcn_mfma_f32_16x16x32_bf16(al[rf], bh, acc[rf][cf], 0, 0, 0);
        acc[rf][cf] = __builtin_amdgcn_mfma_f32_16x16x32_bf16(ah[rf], bl, acc[rf][cf], 0, 0, 0);
      }
    }
  }

  float as_c[8], ad_c[8];
  #pragma unroll
  for (int cf = 0; cf < 8; ++cf){
    as_c[cf] = a_src[cf*16 + l15];
    ad_c[cf] = a_dst[cf*16 + l15];
  }

  #pragma unroll
  for (int rf = 0; rf < 2; ++rf){
    #pragma unroll
    for (int reg = 0; reg < 4; ++reg){
      int gr = row0 + wave*32 + rf*16 + l4*4 + reg;
      bool ok = gr < n;
      if (ok){
        #pragma unroll
        for (int cf = 0; cf < 8; ++cf)
          Hb[(size_t)gr*D + cf*16 + l15] = bf16_rn(acc[rf][cf][reg]);
      }
      float ps = 0.f, pd = 0.f;
      #pragma unroll
      for (int cf = 0; cf < 8; ++cf){
        ps += acc[rf][cf][reg] * as_c[cf];
        pd += acc[rf][cf][reg] * ad_c[cf];
      }
      ps += __shfl_xor(ps, 1); pd += __shfl_xor(pd, 1);
      ps += __shfl_xor(ps, 2); pd += __shfl_xor(pd, 2);
      ps += __shfl_xor(ps, 4); pd += __shfl_xor(pd, 4);
      ps += __shfl_xor(ps, 8); pd += __shfl_xor(pd, 8);
      if (l15 == 0 && ok){ ALs[gr] = ps; ALd[gr] = pd; }
    }
  }
}

// ---------------- per-node softmax stats + unnormalized edge weights ----------------
// One THREAD per node: pass 1 = max over incoming logits; pass 2 = weights + sum.
// ALs is ~400 KB -> L2-resident gathers; 100k threads hide the latency.
__global__ __launch_bounds__(256) void node_softmax_kernel(const float* __restrict__ ALs,
    const float* __restrict__ ALd, const int* __restrict__ row_ptr, const int* __restrict__ col,
    float* __restrict__ w, float* __restrict__ wself, float* __restrict__ zinv, int n)
{
  int i = blockIdx.x*blockDim.x + threadIdx.x;
  if (i >= n) return;
  int beg = row_ptr[i], end = row_ptr[i+1];
  float ald = ALd[i];
  float e_self = lrelu(ALs[i] + ald);
  float m = e_self;
  for (int j = beg; j < end; ++j)
    m = fmaxf(m, lrelu(ALs[col[j]] + ald));
  float ws = __expf(e_self - m);
  float z = ws;
  for (int j = beg; j < end; ++j){
    float ww = __expf(lrelu(ALs[col[j]] + ald) - m);
    w[j] = ww;
    z += ww;
  }
  wself[i] = ws;
  zinv[i]  = 1.f / z;
}

// ---------------- weighted gather aggregation (bf16 h) ----------------
// One wave per node; col/w loads are wave-uniform (scalarized via readfirstlane).
__global__ __launch_bounds__(256) void agg_kernel(const unsigned short* __restrict__ Hb,
    const float* __restrict__ w, const float* __restrict__ wself, const float* __restrict__ zinv,
    const int* __restrict__ row_ptr, const int* __restrict__ col,
    const float* __restrict__ bias, float* __restrict__ out, int n)
{
  int gtid = blockIdx.x*blockDim.x + threadIdx.x;
  int node = __builtin_amdgcn_readfirstlane(gtid >> 6);
  int lane = threadIdx.x & 63;
  if (node >= n) return;

  int beg = __builtin_amdgcn_readfirstlane(row_ptr[node]);
  int end = __builtin_amdgcn_readfirstlane(row_ptr[node+1]);

  const unsigned int* H2 = (const unsigned int*)Hb;
  float ws = wself[node];
  unsigned int us = H2[(size_t)node*64 + lane];
  float2 acc; acc.x = ws * bf16_lo_f(us); acc.y = ws * bf16_hi_f(us);

  int j = beg;
  for (; j + 4 <= end; j += 4){
    int s0 = col[j], s1 = col[j+1], s2 = col[j+2], s3 = col[j+3];
    float w0 = w[j], w1 = w[j+1], w2 = w[j+2], w3 = w[j+3];
    unsigned int u0 = H2[(size_t)s0*64 + lane];
    unsigned int u1 = H2[(size_t)s1*64 + lane];
    unsigned int u2 = H2[(size_t)s2*64 + lane];
    unsigned int u3 = H2[(size_t)s3*64 + lane];
    acc.x += w0*bf16_lo_f(u0); acc.y += w0*bf16_hi_f(u0);
    acc.x += w1*bf16_lo_f(u1); acc.y += w1*bf16_hi_f(u1);
    acc.x += w2*bf16_lo_f(u2); acc.y += w2*bf16_hi_f(u2);
    acc.x += w3*bf16_lo_f(u3); acc.y += w3*bf16_hi_f(u3);
  }
  for (; j < end; ++j){
    int s = col[j];
    float ww = w[j];
    unsigned int u = H2[(size_t)s*64 + lane];
    acc.x += ww*bf16_lo_f(u); acc.y += ww*bf16_hi_f(u);
  }

  float zi = zinv[node];
  float2 b2 = ((const float2*)bias)[lane];
  float2 o; o.x = acc.x*zi + b2.x; o.y = acc.y*zi + b2.y;
  ((float2*)out)[(size_t)node*64 + lane] = o;
}

// ---------------- launch ----------------
extern "C" void kernel_launch(void* const* d_in, const int* in_sizes, int n_in,
                              void* d_out, int out_size, void* d_ws, size_t ws_size,
                              hipStream_t stream)
{
  const float* x   = (const float*)d_in[0];
  const int*   ei  = (const int*)  d_in[1];
  const float* W1  = (const float*)d_in[2];
  const float* as1 = (const float*)d_in[3];
  const float* ad1 = (const float*)d_in[4];
  const float* b1  = (const float*)d_in[5];
  const float* W2  = (const float*)d_in[6];
  const float* as2 = (const float*)d_in[7];
  const float* ad2 = (const float*)d_in[8];
  const float* b2  = (const float*)d_in[9];

  int n = in_sizes[0] / D;
  int E = in_sizes[1] / 2;
  const int* src = ei;
  const int* dst = ei + E;
  int nbuck = (n + BSZ - 1) >> BSH;

  // workspace layout
  unsigned short* hb = (unsigned short*)d_ws;          // n*128 bf16
  float* als = (float*)(hb + (size_t)n*D);             // n
  float* ald = als + n;                                // n
  float* wself = ald + n;                              // n
  float* zinv  = wself + n;                            // n
  int* row_ptr = (int*)(zinv + n);                     // n+1
  int* bcnt  = row_ptr + (n+1);                        // 256
  int* bbase = bcnt + 256;                             // 257
  int* bcur  = bbase + 257;                            // 256 (+pad)
  unsigned short* wh1 = (unsigned short*)(bcur + 259); // 16384 each
  unsigned short* wl1 = wh1 + 16384;
  unsigned short* wh2 = wl1 + 16384;
  unsigned short* wl2 = wh2 + 16384;
  unsigned int* ebuf = (unsigned int*)(wl2 + 16384);   // E
  int* col = (int*)(ebuf + E);                         // E
  float* wedge = (float*)(col + E);                    // E

  float* out = (float*)d_out;

  hipMemsetAsync(bcnt, 0, 256*sizeof(int), stream);
  int sc_blocks = (E + SC_CHUNK - 1) / SC_CHUNK;
  bucket_count_kernel  <<<128, 1024, 0, stream>>>(dst, E, bcnt, nbuck);
  bucket_scan_kernel   <<<1, 256, 0, stream>>>(bcnt, bbase, bcur, nbuck, E);
  bucket_scatter_kernel<<<sc_blocks, 1024, 0, stream>>>(src, dst, E, bcur, ebuf, nbuck);
  bucket_csr_kernel    <<<nbuck, 256, 0, stream>>>(ebuf, bbase, row_ptr, col, n, nbuck);

  wsplit_kernel<<<64, 256, 0, stream>>>(W1, wh1, wl1);
  wsplit_kernel<<<64, 256, 0, stream>>>(W2, wh2, wl2);

  int ntiles = (n + 127)/128;
  int nodeblocks = (n + 255)/256;
  int aggblocks = (int)(((size_t)n*64 + 255)/256);

  gemm_al_kernel     <<<ntiles, 256, 0, stream>>>(x,  wh1, wl1, as1, ad1, hb, als, ald, n);
  node_softmax_kernel<<<nodeblocks, 256, 0, stream>>>(als, ald, row_ptr, col, wedge, wself, zinv, n);
  agg_kernel         <<<aggblocks, 256, 0, stream>>>(hb, wedge, wself, zinv, row_ptr, col, b1, out, n);
  gemm_al_kernel     <<<ntiles, 256, 0, stream>>>(out, wh2, wl2, as2, ad2, hb, als, ald, n);
  node_softmax_kernel<<<nodeblocks, 256, 0, stream>>>(als, ald, row_ptr, col, wedge, wself, zinv, n);
  agg_kernel         <<<aggblocks, 256, 0, stream>>>(hb, wedge, wself, zinv, row_ptr, col, b2, out, n);
}

// Round 7
// 331.015 us; speedup vs baseline: 1.0878x; 1.0878x over previous
//
#include <hip/hip_runtime.h>
#include <hip/hip_bf16.h>
#include <math.h>

#define D 128
#define LRELU_SLOPE 0.2f
#define BSH 9
#define BSZ 512
#define SC_CHUNK 16384

typedef __attribute__((ext_vector_type(8))) short bf16x8;
typedef __attribute__((ext_vector_type(4))) float f32x4;

__device__ __forceinline__ float lrelu(float x){ return x > 0.f ? x : LRELU_SLOPE * x; }

__device__ __forceinline__ unsigned short bf16_rn(float x){
  unsigned int u = __float_as_uint(x);
  return (unsigned short)((u + 0x7FFFu + ((u >> 16) & 1u)) >> 16);
}
__device__ __forceinline__ float bf16_lo_f(unsigned int u){ return __uint_as_float(u << 16); }
__device__ __forceinline__ float bf16_hi_f(unsigned int u){ return __uint_as_float(u & 0xFFFF0000u); }

// ---------------- bucketed CSR build ----------------
__global__ __launch_bounds__(1024) void bucket_count_kernel(const int* __restrict__ dst, int E,
    int* __restrict__ bcnt, int nbuck){
  __shared__ int h[256];
  int t = threadIdx.x;
  if (t < 256) h[t] = 0;
  __syncthreads();
  for (int e = blockIdx.x*1024 + t; e < E; e += gridDim.x*1024)
    atomicAdd(&h[dst[e] >> BSH], 1);
  __syncthreads();
  if (t < nbuck && h[t]) atomicAdd(&bcnt[t], h[t]);
}

__global__ __launch_bounds__(256) void bucket_scan_kernel(const int* __restrict__ bcnt,
    int* __restrict__ bbase, int* __restrict__ bcur, int nbuck, int E){
  __shared__ int s[256];
  int t = threadIdx.x;
  int v = (t < nbuck) ? bcnt[t] : 0;
  s[t] = v;
  __syncthreads();
  #pragma unroll
  for (int d = 1; d < 256; d <<= 1){
    int add = (t >= d) ? s[t-d] : 0;
    __syncthreads();
    s[t] += add;
    __syncthreads();
  }
  if (t < nbuck){ int b = s[t] - v; bbase[t] = b; bcur[t] = b; }
  if (t == 0) bbase[nbuck] = E;
}

__global__ __launch_bounds__(1024) void bucket_scatter_kernel(const int* __restrict__ src,
    const int* __restrict__ dst, int E, int* __restrict__ bcur,
    unsigned int* __restrict__ ebuf, int nbuck){
  __shared__ int h[256];
  __shared__ int cb[256];
  int t = threadIdx.x;
  int base = blockIdx.x * SC_CHUNK;
  int end = base + SC_CHUNK; if (end > E) end = E;
  if (t < 256) h[t] = 0;
  __syncthreads();
  for (int e = base + t; e < end; e += 1024)
    atomicAdd(&h[dst[e] >> BSH], 1);
  __syncthreads();
  if (t < nbuck){
    cb[t] = h[t] ? atomicAdd(&bcur[t], h[t]) : 0;
    h[t] = 0;
  }
  __syncthreads();
  for (int e = base + t; e < end; e += 1024){
    int d = dst[e];
    int b = d >> BSH;
    int lpos = atomicAdd(&h[b], 1);
    ebuf[cb[b] + lpos] = ((unsigned int)src[e] << BSH) | (unsigned int)(d & (BSZ-1));
  }
}

__global__ __launch_bounds__(256) void bucket_csr_kernel(const unsigned int* __restrict__ ebuf,
    const int* __restrict__ bbase, int* __restrict__ row_ptr, int* __restrict__ col,
    int n, int nbuck){
  __shared__ int c[512];
  __shared__ int ps[256];
  int b = blockIdx.x;
  int t = threadIdx.x;
  int base = bbase[b], end = bbase[b+1];
  c[t] = 0; c[t+256] = 0;
  __syncthreads();
  for (int i = base + t; i < end; i += 256)
    atomicAdd(&c[ebuf[i] & (BSZ-1)], 1);
  __syncthreads();
  int a0 = c[2*t], a1 = c[2*t+1];
  int pair = a0 + a1;
  ps[t] = pair;
  __syncthreads();
  #pragma unroll
  for (int d = 1; d < 256; d <<= 1){
    int add = (t >= d) ? ps[t-d] : 0;
    __syncthreads();
    ps[t] += add;
    __syncthreads();
  }
  int excl = ps[t] - pair;
  __syncthreads();
  int lo = b << BSH;
  int g0 = lo + 2*t, g1 = g0 + 1;
  if (g0 < n) row_ptr[g0] = base + excl;
  if (g1 < n) row_ptr[g1] = base + excl + a0;
  c[2*t]   = excl;
  c[2*t+1] = excl + a0;
  __syncthreads();
  for (int i = base + t; i < end; i += 256){
    unsigned int p = ebuf[i];
    int dlo = p & (BSZ-1);
    int pos = base + atomicAdd(&c[dlo], 1);
    col[pos] = (int)(p >> BSH);
  }
  if (b == 0 && t == 0) row_ptr[n] = bbase[nbuck];
}

// ---------------- W pre-split into per-wave MFMA fragment layout ----------------
// Fragment slot (kc,cf) holds 64 lanes x 8 bf16 contiguously (1KB):
//   dest = ((kc*8+cf)*64 + l4*16 + l15)*8 + e,  where k=(kc*4+l4)*8+e, nn=cf*16+l15.
__global__ __launch_bounds__(256) void wsplit_kernel(const float* __restrict__ W,
    unsigned short* __restrict__ Whf, unsigned short* __restrict__ Wlf){
  int t = blockIdx.x*256 + threadIdx.x;   // 0..16383
  int k  = t >> 7;
  int nn = t & 127;
  float w = W[t];
  unsigned short h = bf16_rn(w);
  float whf = __uint_as_float(((unsigned int)h) << 16);
  unsigned short l = bf16_rn(w - whf);
  int kc = k >> 5, l4 = (k >> 3) & 3, e = k & 7;
  int cf = nn >> 4, l15 = nn & 15;
  int idx = ((kc*8 + cf)*64 + l4*16 + l15)*8 + e;
  Whf[idx] = h; Wlf[idx] = l;
}

// ---------------- Wa = W @ a  (per-layer 128-vector for exact fp32 logits) ----------------
__global__ __launch_bounds__(64) void wa_kernel(const float* __restrict__ W,
    const float* __restrict__ a_src, const float* __restrict__ a_dst,
    float* __restrict__ wa_s, float* __restrict__ wa_d){
  int task = blockIdx.x;           // 0..255
  int row = task & 127;
  const float* a = (task >> 7) ? a_dst : a_src;
  int l = threadIdx.x;
  float2 v = ((const float2*)(W + row*D))[l];
  float p = v.x*a[2*l] + v.y*a[2*l+1];
  #pragma unroll
  for (int off = 32; off >= 1; off >>= 1) p += __shfl_xor(p, off);
  if (l == 0) ((task >> 7) ? wa_d : wa_s)[row] = p;
}

// ---------------- MFMA bf16 GEMM (2-term: xh*wh + xh*wl) + exact fp32 logits ----------------
// Block: 256 threads (4 waves), tile 128 rows. LDS: Xh only (32 KB).
// W fragments read straight from global (64 KB, L2-resident, coalesced 1KB/wave).
// Logits computed fp32 during staging via precomputed Wa vectors.
__global__ __launch_bounds__(256) void gemm_al_kernel(const float* __restrict__ X,
    const unsigned short* __restrict__ Whf, const unsigned short* __restrict__ Wlf,
    const float* __restrict__ Wa_src, const float* __restrict__ Wa_dst,
    unsigned short* __restrict__ Hb, float* __restrict__ ALs, float* __restrict__ ALd, int n)
{
  __shared__ unsigned short Xh[128*128];   // 32 KB
  int tid  = threadIdx.x;
  int lane = tid & 63;
  int wave = tid >> 6;
  int row0 = blockIdx.x * 128;
  int c4   = tid & 31;

  float4 wa_s4 = ((const float4*)Wa_src)[c4];
  float4 wa_d4 = ((const float4*)Wa_dst)[c4];

  // ---- stage Xh (swizzled) + fp32 logits ----
  #pragma unroll 4
  for (int it = 0; it < 16; ++it){
    int f  = it*256 + tid;
    int r  = f >> 5;
    float4 v = make_float4(0.f,0.f,0.f,0.f);
    int gr = row0 + r;
    if (gr < n) v = ((const float4*)(X + (size_t)gr*D))[c4];
    unsigned short h0 = bf16_rn(v.x);
    unsigned short h1 = bf16_rn(v.y);
    unsigned short h2 = bf16_rn(v.z);
    unsigned short h3 = bf16_rn(v.w);
    int g   = (c4 >> 1) ^ (r & 7);
    int idx = r*128 + (g << 3) + ((c4 & 1) << 2);
    *(uint2*)&Xh[idx] = make_uint2((unsigned)h0 | ((unsigned)h1<<16),
                                   (unsigned)h2 | ((unsigned)h3<<16));
    float ps = v.x*wa_s4.x + v.y*wa_s4.y + v.z*wa_s4.z + v.w*wa_s4.w;
    float pd = v.x*wa_d4.x + v.y*wa_d4.y + v.z*wa_d4.z + v.w*wa_d4.w;
    #pragma unroll
    for (int off = 16; off >= 1; off >>= 1){
      ps += __shfl_xor(ps, off);
      pd += __shfl_xor(pd, off);
    }
    if ((tid & 31) == 0 && gr < n){ ALs[gr] = ps; ALd[gr] = pd; }
  }
  __syncthreads();

  int l15 = lane & 15;
  int l4  = lane >> 4;

  f32x4 acc[2][8];
  #pragma unroll
  for (int rf = 0; rf < 2; ++rf)
    #pragma unroll
    for (int cf = 0; cf < 8; ++cf)
      acc[rf][cf] = (f32x4){0.f, 0.f, 0.f, 0.f};

  #pragma unroll
  for (int kc = 0; kc < 4; ++kc){
    int g = kc*4 + l4;
    bf16x8 ah[2];
    #pragma unroll
    for (int rf = 0; rf < 2; ++rf){
      int r   = wave*32 + rf*16 + l15;
      int idx = r*128 + ((g ^ (r & 7)) << 3);
      ah[rf] = *(const bf16x8*)&Xh[idx];
    }
    #pragma unroll
    for (int cf = 0; cf < 8; ++cf){
      int foff = ((kc*8 + cf) << 9) + (lane << 3);
      bf16x8 bh = *(const bf16x8*)&Whf[foff];
      bf16x8 bl = *(const bf16x8*)&Wlf[foff];
      #pragma unroll
      for (int rf = 0; rf < 2; ++rf){
        acc[rf][cf] = __builtin_amdgcn_mfma_f32_16x16x32_bf16(ah[rf], bh, acc[rf][cf], 0, 0, 0);
        acc[rf][cf] = __builtin_amdgcn_mfma_f32_16x16x32_bf16(ah[rf], bl, acc[rf][cf], 0, 0, 0);
      }
    }
  }

  // ---- epilogue: store H (bf16) ----
  #pragma unroll
  for (int rf = 0; rf < 2; ++rf){
    #pragma unroll
    for (int reg = 0; reg < 4; ++reg){
      int gr = row0 + wave*32 + rf*16 + l4*4 + reg;   // C/D: row=(lane>>4)*4+reg
      if (gr < n){
        #pragma unroll
        for (int cf = 0; cf < 8; ++cf)
          Hb[(size_t)gr*D + cf*16 + l15] = bf16_rn(acc[rf][cf][reg]);  // col = lane&15
      }
    }
  }
}

// ---------------- per-node softmax stats + unnormalized edge weights ----------------
__global__ __launch_bounds__(256) void node_softmax_kernel(const float* __restrict__ ALs,
    const float* __restrict__ ALd, const int* __restrict__ row_ptr, const int* __restrict__ col,
    float* __restrict__ w, float* __restrict__ wself, float* __restrict__ zinv, int n)
{
  int i = blockIdx.x*blockDim.x + threadIdx.x;
  if (i >= n) return;
  int beg = row_ptr[i], end = row_ptr[i+1];
  float ald = ALd[i];
  float e_self = lrelu(ALs[i] + ald);
  float m = e_self;
  for (int j = beg; j < end; ++j)
    m = fmaxf(m, lrelu(ALs[col[j]] + ald));
  float ws = __expf(e_self - m);
  float z = ws;
  for (int j = beg; j < end; ++j){
    float ww = __expf(lrelu(ALs[col[j]] + ald) - m);
    w[j] = ww;
    z += ww;
  }
  wself[i] = ws;
  zinv[i]  = 1.f / z;
}

// ---------------- weighted gather aggregation (bf16 h, unroll-8 ILP) ----------------
__global__ __launch_bounds__(256) void agg_kernel(const unsigned short* __restrict__ Hb,
    const float* __restrict__ w, const float* __restrict__ wself, const float* __restrict__ zinv,
    const int* __restrict__ row_ptr, const int* __restrict__ col,
    const float* __restrict__ bias, float* __restrict__ out, int n)
{
  int gtid = blockIdx.x*blockDim.x + threadIdx.x;
  int node = __builtin_amdgcn_readfirstlane(gtid >> 6);
  int lane = threadIdx.x & 63;
  if (node >= n) return;

  int beg = __builtin_amdgcn_readfirstlane(row_ptr[node]);
  int end = __builtin_amdgcn_readfirstlane(row_ptr[node+1]);

  const unsigned int* H2 = (const unsigned int*)Hb;
  float ws = wself[node];
  unsigned int us = H2[(size_t)node*64 + lane];
  float2 acc; acc.x = ws * bf16_lo_f(us); acc.y = ws * bf16_hi_f(us);

  int j = beg;
  for (; j + 8 <= end; j += 8){
    int   s[8]; float wv[8]; unsigned int u[8];
    #pragma unroll
    for (int q = 0; q < 8; ++q){ s[q] = col[j+q]; wv[q] = w[j+q]; }
    #pragma unroll
    for (int q = 0; q < 8; ++q) u[q] = H2[(size_t)s[q]*64 + lane];
    #pragma unroll
    for (int q = 0; q < 8; ++q){
      acc.x += wv[q]*bf16_lo_f(u[q]);
      acc.y += wv[q]*bf16_hi_f(u[q]);
    }
  }
  for (; j < end; ++j){
    int sx = col[j];
    float ww = w[j];
    unsigned int u = H2[(size_t)sx*64 + lane];
    acc.x += ww*bf16_lo_f(u); acc.y += ww*bf16_hi_f(u);
  }

  float zi = zinv[node];
  float2 b2 = ((const float2*)bias)[lane];
  float2 o; o.x = acc.x*zi + b2.x; o.y = acc.y*zi + b2.y;
  ((float2*)out)[(size_t)node*64 + lane] = o;
}

// ---------------- launch ----------------
extern "C" void kernel_launch(void* const* d_in, const int* in_sizes, int n_in,
                              void* d_out, int out_size, void* d_ws, size_t ws_size,
                              hipStream_t stream)
{
  const float* x   = (const float*)d_in[0];
  const int*   ei  = (const int*)  d_in[1];
  const float* W1  = (const float*)d_in[2];
  const float* as1 = (const float*)d_in[3];
  const float* ad1 = (const float*)d_in[4];
  const float* b1  = (const float*)d_in[5];
  const float* W2  = (const float*)d_in[6];
  const float* as2 = (const float*)d_in[7];
  const float* ad2 = (const float*)d_in[8];
  const float* b2  = (const float*)d_in[9];

  int n = in_sizes[0] / D;
  int E = in_sizes[1] / 2;
  const int* src = ei;
  const int* dst = ei + E;
  int nbuck = (n + BSZ - 1) >> BSH;

  // workspace layout (256B-aligned chunks)
  char* base = (char*)d_ws;
  size_t off = 0;
  auto alloc = [&](size_t bytes) -> char* {
    char* p = base + off;
    off = (off + bytes + 255) & ~(size_t)255;
    return p;
  };
  unsigned short* hb = (unsigned short*)alloc((size_t)n*D*2);
  float* als   = (float*)alloc((size_t)n*4);
  float* ald   = (float*)alloc((size_t)n*4);
  float* wself = (float*)alloc((size_t)n*4);
  float* zinv  = (float*)alloc((size_t)n*4);
  int* row_ptr = (int*)alloc((size_t)(n+1)*4);
  int* bcnt    = (int*)alloc(256*4);
  int* bbase   = (int*)alloc(257*4);
  int* bcur    = (int*)alloc(256*4);
  unsigned short* whf1 = (unsigned short*)alloc(16384*2);
  unsigned short* wlf1 = (unsigned short*)alloc(16384*2);
  unsigned short* whf2 = (unsigned short*)alloc(16384*2);
  unsigned short* wlf2 = (unsigned short*)alloc(16384*2);
  float* wa_s1 = (float*)alloc(128*4);
  float* wa_d1 = (float*)alloc(128*4);
  float* wa_s2 = (float*)alloc(128*4);
  float* wa_d2 = (float*)alloc(128*4);
  unsigned int* ebuf = (unsigned int*)alloc((size_t)E*4);
  int* col   = (int*)alloc((size_t)E*4);
  float* wedge = (float*)alloc((size_t)E*4);

  float* out = (float*)d_out;

  hipMemsetAsync(bcnt, 0, 256*sizeof(int), stream);
  int sc_blocks = (E + SC_CHUNK - 1) / SC_CHUNK;
  bucket_count_kernel  <<<128, 1024, 0, stream>>>(dst, E, bcnt, nbuck);
  bucket_scan_kernel   <<<1, 256, 0, stream>>>(bcnt, bbase, bcur, nbuck, E);
  bucket_scatter_kernel<<<sc_blocks, 1024, 0, stream>>>(src, dst, E, bcur, ebuf, nbuck);
  bucket_csr_kernel    <<<nbuck, 256, 0, stream>>>(ebuf, bbase, row_ptr, col, n, nbuck);

  wsplit_kernel<<<64, 256, 0, stream>>>(W1, whf1, wlf1);
  wsplit_kernel<<<64, 256, 0, stream>>>(W2, whf2, wlf2);
  wa_kernel    <<<256, 64, 0, stream>>>(W1, as1, ad1, wa_s1, wa_d1);
  wa_kernel    <<<256, 64, 0, stream>>>(W2, as2, ad2, wa_s2, wa_d2);

  int ntiles = (n + 127)/128;
  int nodeblocks = (n + 255)/256;
  int aggblocks = (int)(((size_t)n*64 + 255)/256);

  gemm_al_kernel     <<<ntiles, 256, 0, stream>>>(x,  whf1, wlf1, wa_s1, wa_d1, hb, als, ald, n);
  node_softmax_kernel<<<nodeblocks, 256, 0, stream>>>(als, ald, row_ptr, col, wedge, wself, zinv, n);
  agg_kernel         <<<aggblocks, 256, 0, stream>>>(hb, wedge, wself, zinv, row_ptr, col, b1, out, n);
  gemm_al_kernel     <<<ntiles, 256, 0, stream>>>(out, whf2, wlf2, wa_s2, wa_d2, hb, als, ald, n);
  node_softmax_kernel<<<nodeblocks, 256, 0, stream>>>(als, ald, row_ptr, col, wedge, wself, zinv, n);
  agg_kernel         <<<aggblocks, 256, 0, stream>>>(hb, wedge, wself, zinv, row_ptr, col, b2, out, n);
}

// Round 8
// 288.339 us; speedup vs baseline: 1.2488x; 1.1480x over previous
//
#include <hip/hip_runtime.h>
#include <hip/hip_bf16.h>
#include <math.h>

#define D 128
#define LRELU_SLOPE 0.2f
#define BSH 9
#define BSZ 512
#define SC_CHUNK 16384

typedef __attribute__((ext_vector_type(8))) short bf16x8;
typedef __attribute__((ext_vector_type(4))) float f32x4;

__device__ __forceinline__ float lrelu(float x){ return x > 0.f ? x : LRELU_SLOPE * x; }

__device__ __forceinline__ unsigned short bf16_rn(float x){
  unsigned int u = __float_as_uint(x);
  return (unsigned short)((u + 0x7FFFu + ((u >> 16) & 1u)) >> 16);
}
__device__ __forceinline__ float bf16_lo_f(unsigned int u){ return __uint_as_float(u << 16); }
__device__ __forceinline__ float bf16_hi_f(unsigned int u){ return __uint_as_float(u & 0xFFFF0000u); }

// ---------------- bucketed CSR build ----------------
__global__ __launch_bounds__(1024) void bucket_count_kernel(const int* __restrict__ dst, int E,
    int* __restrict__ bcnt, int nbuck){
  __shared__ int h[256];
  int t = threadIdx.x;
  if (t < 256) h[t] = 0;
  __syncthreads();
  for (int e = blockIdx.x*1024 + t; e < E; e += gridDim.x*1024)
    atomicAdd(&h[dst[e] >> BSH], 1);
  __syncthreads();
  if (t < nbuck && h[t]) atomicAdd(&bcnt[t], h[t]);
}

__global__ __launch_bounds__(256) void bucket_scan_kernel(const int* __restrict__ bcnt,
    int* __restrict__ bbase, int* __restrict__ bcur, int nbuck, int E){
  __shared__ int s[256];
  int t = threadIdx.x;
  int v = (t < nbuck) ? bcnt[t] : 0;
  s[t] = v;
  __syncthreads();
  #pragma unroll
  for (int d = 1; d < 256; d <<= 1){
    int add = (t >= d) ? s[t-d] : 0;
    __syncthreads();
    s[t] += add;
    __syncthreads();
  }
  if (t < nbuck){ int b = s[t] - v; bbase[t] = b; bcur[t] = b; }
  if (t == 0) bbase[nbuck] = E;
}

__global__ __launch_bounds__(1024) void bucket_scatter_kernel(const int* __restrict__ src,
    const int* __restrict__ dst, int E, int* __restrict__ bcur,
    unsigned int* __restrict__ ebuf, int nbuck){
  __shared__ int h[256];
  __shared__ int cb[256];
  int t = threadIdx.x;
  int base = blockIdx.x * SC_CHUNK;
  int end = base + SC_CHUNK; if (end > E) end = E;
  if (t < 256) h[t] = 0;
  __syncthreads();
  for (int e = base + t; e < end; e += 1024)
    atomicAdd(&h[dst[e] >> BSH], 1);
  __syncthreads();
  if (t < nbuck){
    cb[t] = h[t] ? atomicAdd(&bcur[t], h[t]) : 0;
    h[t] = 0;
  }
  __syncthreads();
  for (int e = base + t; e < end; e += 1024){
    int d = dst[e];
    int b = d >> BSH;
    int lpos = atomicAdd(&h[b], 1);
    ebuf[cb[b] + lpos] = ((unsigned int)src[e] << BSH) | (unsigned int)(d & (BSZ-1));
  }
}

__global__ __launch_bounds__(256) void bucket_csr_kernel(const unsigned int* __restrict__ ebuf,
    const int* __restrict__ bbase, int* __restrict__ row_ptr, int* __restrict__ col,
    int n, int nbuck){
  __shared__ int c[512];
  __shared__ int ps[256];
  int b = blockIdx.x;
  int t = threadIdx.x;
  int base = bbase[b], end = bbase[b+1];
  c[t] = 0; c[t+256] = 0;
  __syncthreads();
  for (int i = base + t; i < end; i += 256)
    atomicAdd(&c[ebuf[i] & (BSZ-1)], 1);
  __syncthreads();
  int a0 = c[2*t], a1 = c[2*t+1];
  int pair = a0 + a1;
  ps[t] = pair;
  __syncthreads();
  #pragma unroll
  for (int d = 1; d < 256; d <<= 1){
    int add = (t >= d) ? ps[t-d] : 0;
    __syncthreads();
    ps[t] += add;
    __syncthreads();
  }
  int excl = ps[t] - pair;
  __syncthreads();
  int lo = b << BSH;
  int g0 = lo + 2*t, g1 = g0 + 1;
  if (g0 < n) row_ptr[g0] = base + excl;
  if (g1 < n) row_ptr[g1] = base + excl + a0;
  c[2*t]   = excl;
  c[2*t+1] = excl + a0;
  __syncthreads();
  for (int i = base + t; i < end; i += 256){
    unsigned int p = ebuf[i];
    int dlo = p & (BSZ-1);
    int pos = base + atomicAdd(&c[dlo], 1);
    col[pos] = (int)(p >> BSH);
  }
  if (b == 0 && t == 0) row_ptr[n] = bbase[nbuck];
}

// ---------------- W pre-split into per-wave MFMA fragment layout ----------------
__global__ __launch_bounds__(256) void wsplit_kernel(const float* __restrict__ W,
    unsigned short* __restrict__ Whf, unsigned short* __restrict__ Wlf){
  int t = blockIdx.x*256 + threadIdx.x;   // 0..16383
  int k  = t >> 7;
  int nn = t & 127;
  float w = W[t];
  unsigned short h = bf16_rn(w);
  float whf = __uint_as_float(((unsigned int)h) << 16);
  unsigned short l = bf16_rn(w - whf);
  int kc = k >> 5, l4 = (k >> 3) & 3, e = k & 7;
  int cf = nn >> 4, l15 = nn & 15;
  int idx = ((kc*8 + cf)*64 + l4*16 + l15)*8 + e;
  Whf[idx] = h; Wlf[idx] = l;
}

// ---------------- Wa = W @ a ----------------
__global__ __launch_bounds__(64) void wa_kernel(const float* __restrict__ W,
    const float* __restrict__ a_src, const float* __restrict__ a_dst,
    float* __restrict__ wa_s, float* __restrict__ wa_d){
  int task = blockIdx.x;           // 0..255
  int row = task & 127;
  const float* a = (task >> 7) ? a_dst : a_src;
  int l = threadIdx.x;
  float2 v = ((const float2*)(W + row*D))[l];
  float p = v.x*a[2*l] + v.y*a[2*l+1];
  #pragma unroll
  for (int off = 32; off >= 1; off >>= 1) p += __shfl_xor(p, off);
  if (l == 0) ((task >> 7) ? wa_d : wa_s)[row] = p;
}

// ---------------- MFMA bf16 GEMM (2-term) + exact fp32 logits ----------------
// Hb stored in PERMUTED row layout: ushort p of row r holds H[r][(p&7)*16 + (p>>3)],
// so the MFMA epilogue stores one uint4 per (rf,reg) -- fully coalesced.
__global__ __launch_bounds__(256) void gemm_al_kernel(const float* __restrict__ X,
    const unsigned short* __restrict__ Whf, const unsigned short* __restrict__ Wlf,
    const float* __restrict__ Wa_src, const float* __restrict__ Wa_dst,
    unsigned short* __restrict__ Hb, float* __restrict__ ALs, float* __restrict__ ALd, int n)
{
  __shared__ unsigned short Xh[128*128];   // 32 KB
  int tid  = threadIdx.x;
  int lane = tid & 63;
  int wave = tid >> 6;
  int row0 = blockIdx.x * 128;
  int c4   = tid & 31;

  float4 wa_s4 = ((const float4*)Wa_src)[c4];
  float4 wa_d4 = ((const float4*)Wa_dst)[c4];

  // ---- stage Xh (swizzled) + fp32 logits ----
  #pragma unroll 4
  for (int it = 0; it < 16; ++it){
    int f  = it*256 + tid;
    int r  = f >> 5;
    float4 v = make_float4(0.f,0.f,0.f,0.f);
    int gr = row0 + r;
    if (gr < n) v = ((const float4*)(X + (size_t)gr*D))[c4];
    unsigned short h0 = bf16_rn(v.x);
    unsigned short h1 = bf16_rn(v.y);
    unsigned short h2 = bf16_rn(v.z);
    unsigned short h3 = bf16_rn(v.w);
    int g   = (c4 >> 1) ^ (r & 7);
    int idx = r*128 + (g << 3) + ((c4 & 1) << 2);
    *(uint2*)&Xh[idx] = make_uint2((unsigned)h0 | ((unsigned)h1<<16),
                                   (unsigned)h2 | ((unsigned)h3<<16));
    float ps = v.x*wa_s4.x + v.y*wa_s4.y + v.z*wa_s4.z + v.w*wa_s4.w;
    float pd = v.x*wa_d4.x + v.y*wa_d4.y + v.z*wa_d4.z + v.w*wa_d4.w;
    #pragma unroll
    for (int off = 16; off >= 1; off >>= 1){
      ps += __shfl_xor(ps, off);
      pd += __shfl_xor(pd, off);
    }
    if ((tid & 31) == 0 && gr < n){ ALs[gr] = ps; ALd[gr] = pd; }
  }
  __syncthreads();

  int l15 = lane & 15;
  int l4  = lane >> 4;

  f32x4 acc[2][8];
  #pragma unroll
  for (int rf = 0; rf < 2; ++rf)
    #pragma unroll
    for (int cf = 0; cf < 8; ++cf)
      acc[rf][cf] = (f32x4){0.f, 0.f, 0.f, 0.f};

  #pragma unroll
  for (int kc = 0; kc < 4; ++kc){
    int g = kc*4 + l4;
    bf16x8 ah[2];
    #pragma unroll
    for (int rf = 0; rf < 2; ++rf){
      int r   = wave*32 + rf*16 + l15;
      int idx = r*128 + ((g ^ (r & 7)) << 3);
      ah[rf] = *(const bf16x8*)&Xh[idx];
    }
    #pragma unroll
    for (int cf = 0; cf < 8; ++cf){
      int foff = ((kc*8 + cf) << 9) + (lane << 3);
      bf16x8 bh = *(const bf16x8*)&Whf[foff];
      bf16x8 bl = *(const bf16x8*)&Wlf[foff];
      #pragma unroll
      for (int rf = 0; rf < 2; ++rf){
        acc[rf][cf] = __builtin_amdgcn_mfma_f32_16x16x32_bf16(ah[rf], bh, acc[rf][cf], 0, 0, 0);
        acc[rf][cf] = __builtin_amdgcn_mfma_f32_16x16x32_bf16(ah[rf], bl, acc[rf][cf], 0, 0, 0);
      }
    }
  }

  // ---- epilogue: coalesced uint4 stores in permuted layout ----
  #pragma unroll
  for (int rf = 0; rf < 2; ++rf){
    #pragma unroll
    for (int reg = 0; reg < 4; ++reg){
      int gr = row0 + wave*32 + rf*16 + l4*4 + reg;   // C/D: row=(lane>>4)*4+reg
      if (gr < n){
        unsigned int p0 = (unsigned)bf16_rn(acc[rf][0][reg]) | ((unsigned)bf16_rn(acc[rf][1][reg]) << 16);
        unsigned int p1 = (unsigned)bf16_rn(acc[rf][2][reg]) | ((unsigned)bf16_rn(acc[rf][3][reg]) << 16);
        unsigned int p2 = (unsigned)bf16_rn(acc[rf][4][reg]) | ((unsigned)bf16_rn(acc[rf][5][reg]) << 16);
        unsigned int p3 = (unsigned)bf16_rn(acc[rf][6][reg]) | ((unsigned)bf16_rn(acc[rf][7][reg]) << 16);
        ((uint4*)(Hb + (size_t)gr*D))[l15] = make_uint4(p0, p1, p2, p3);
      }
    }
  }
}

// ---------------- fused softmax + weighted gather aggregation ----------------
// One wave per node. Per 64-edge chunk: lane q computes logit/weight for edge beg+q
// (coalesced col load + L2-hot ALs gather, shfl reduces), then the gather loop
// broadcasts (s,w) from lane q via __shfl. Hb is in the permuted layout; a 4-shuffle
// fix-up restores standard column order before the out write.
__global__ __launch_bounds__(256) void agg_kernel(const unsigned short* __restrict__ Hb,
    const float* __restrict__ ALs, const float* __restrict__ ALd,
    const int* __restrict__ row_ptr, const int* __restrict__ col,
    const float* __restrict__ bias, float* __restrict__ out, int n)
{
  int gtid = blockIdx.x*blockDim.x + threadIdx.x;
  int node = gtid >> 6;
  int lane = threadIdx.x & 63;
  if (node >= n) return;

  int beg = row_ptr[node], end = row_ptr[node+1];
  float ald = ALd[node];
  float e_self = lrelu(ALs[node] + ald);

  const unsigned int* H2 = (const unsigned int*)Hb;
  unsigned int us = H2[(size_t)node*64 + lane];
  float2 acc; acc.x = bf16_lo_f(us); acc.y = bf16_hi_f(us);   // weight exp(e_self-m)=1
  float m = e_self, z = 1.f;

  for (int c = beg; c < end; c += 64){
    int j = c + lane;
    bool valid = j < end;
    int s_l = valid ? col[j] : 0;
    float e_l = valid ? lrelu(ALs[s_l] + ald) : -1e30f;

    float mc = e_l;
    #pragma unroll
    for (int off = 32; off >= 1; off >>= 1) mc = fmaxf(mc, __shfl_xor(mc, off));
    if (mc > m){                        // wave-uniform
      float sc = __expf(m - mc);
      z *= sc; acc.x *= sc; acc.y *= sc;
      m = mc;
    }
    float w_l = valid ? __expf(e_l - m) : 0.f;
    float zs = w_l;
    #pragma unroll
    for (int off = 32; off >= 1; off >>= 1) zs += __shfl_xor(zs, off);
    z += zs;

    int cnt = end - c; if (cnt > 64) cnt = 64;
    int q = 0;
    for (; q + 8 <= cnt; q += 8){
      int ss[8]; float ww[8]; unsigned int u[8];
      #pragma unroll
      for (int p = 0; p < 8; ++p){ ss[p] = __shfl(s_l, q+p); ww[p] = __shfl(w_l, q+p); }
      #pragma unroll
      for (int p = 0; p < 8; ++p) u[p] = H2[(size_t)ss[p]*64 + lane];
      #pragma unroll
      for (int p = 0; p < 8; ++p){
        acc.x += ww[p]*bf16_lo_f(u[p]);
        acc.y += ww[p]*bf16_hi_f(u[p]);
      }
    }
    for (; q < cnt; ++q){
      int s = __shfl(s_l, q);
      float w = __shfl(w_l, q);
      unsigned int u = H2[(size_t)s*64 + lane];
      acc.x += w*bf16_lo_f(u); acc.y += w*bf16_hi_f(u);
    }
  }

  float zi = 1.f / z;
  acc.x *= zi; acc.y *= zi;

  // permuted -> standard: lane t needs cols 2t (v0) and 2t+1 (v1)
  int q0 = (lane >> 4) + ((lane & 7) << 3);
  int q1 = q0 + 4;
  int hsel = (lane >> 3) & 1;
  float x0 = __shfl(acc.x, q0), y0 = __shfl(acc.y, q0);
  float x1 = __shfl(acc.x, q1), y1 = __shfl(acc.y, q1);
  float v0 = hsel ? y0 : x0;
  float v1 = hsel ? y1 : x1;

  float2 b2 = ((const float2*)bias)[lane];
  ((float2*)out)[(size_t)node*64 + lane] = make_float2(v0 + b2.x, v1 + b2.y);
}

// ---------------- launch ----------------
extern "C" void kernel_launch(void* const* d_in, const int* in_sizes, int n_in,
                              void* d_out, int out_size, void* d_ws, size_t ws_size,
                              hipStream_t stream)
{
  const float* x   = (const float*)d_in[0];
  const int*   ei  = (const int*)  d_in[1];
  const float* W1  = (const float*)d_in[2];
  const float* as1 = (const float*)d_in[3];
  const float* ad1 = (const float*)d_in[4];
  const float* b1  = (const float*)d_in[5];
  const float* W2  = (const float*)d_in[6];
  const float* as2 = (const float*)d_in[7];
  const float* ad2 = (const float*)d_in[8];
  const float* b2  = (const float*)d_in[9];

  int n = in_sizes[0] / D;
  int E = in_sizes[1] / 2;
  const int* src = ei;
  const int* dst = ei + E;
  int nbuck = (n + BSZ - 1) >> BSH;

  // workspace layout (256B-aligned chunks)
  char* base = (char*)d_ws;
  size_t off = 0;
  auto alloc = [&](size_t bytes) -> char* {
    char* p = base + off;
    off = (off + bytes + 255) & ~(size_t)255;
    return p;
  };
  unsigned short* hb = (unsigned short*)alloc((size_t)n*D*2);
  float* als   = (float*)alloc((size_t)n*4);
  float* ald   = (float*)alloc((size_t)n*4);
  int* row_ptr = (int*)alloc((size_t)(n+1)*4);
  int* bcnt    = (int*)alloc(256*4);
  int* bbase   = (int*)alloc(257*4);
  int* bcur    = (int*)alloc(256*4);
  unsigned short* whf1 = (unsigned short*)alloc(16384*2);
  unsigned short* wlf1 = (unsigned short*)alloc(16384*2);
  unsigned short* whf2 = (unsigned short*)alloc(16384*2);
  unsigned short* wlf2 = (unsigned short*)alloc(16384*2);
  float* wa_s1 = (float*)alloc(128*4);
  float* wa_d1 = (float*)alloc(128*4);
  float* wa_s2 = (float*)alloc(128*4);
  float* wa_d2 = (float*)alloc(128*4);
  unsigned int* ebuf = (unsigned int*)alloc((size_t)E*4);
  int* col   = (int*)alloc((size_t)E*4);

  float* out = (float*)d_out;

  hipMemsetAsync(bcnt, 0, 256*sizeof(int), stream);
  int sc_blocks = (E + SC_CHUNK - 1) / SC_CHUNK;
  bucket_count_kernel  <<<128, 1024, 0, stream>>>(dst, E, bcnt, nbuck);
  bucket_scan_kernel   <<<1, 256, 0, stream>>>(bcnt, bbase, bcur, nbuck, E);
  bucket_scatter_kernel<<<sc_blocks, 1024, 0, stream>>>(src, dst, E, bcur, ebuf, nbuck);
  bucket_csr_kernel    <<<nbuck, 256, 0, stream>>>(ebuf, bbase, row_ptr, col, n, nbuck);

  wsplit_kernel<<<64, 256, 0, stream>>>(W1, whf1, wlf1);
  wsplit_kernel<<<64, 256, 0, stream>>>(W2, whf2, wlf2);
  wa_kernel    <<<256, 64, 0, stream>>>(W1, as1, ad1, wa_s1, wa_d1);
  wa_kernel    <<<256, 64, 0, stream>>>(W2, as2, ad2, wa_s2, wa_d2);

  int ntiles = (n + 127)/128;
  int aggblocks = (int)(((size_t)n*64 + 255)/256);

  gemm_al_kernel<<<ntiles, 256, 0, stream>>>(x,  whf1, wlf1, wa_s1, wa_d1, hb, als, ald, n);
  agg_kernel    <<<aggblocks, 256, 0, stream>>>(hb, als, ald, row_ptr, col, b1, out, n);
  gemm_al_kernel<<<ntiles, 256, 0, stream>>>(out, whf2, wlf2, wa_s2, wa_d2, hb, als, ald, n);
  agg_kernel    <<<aggblocks, 256, 0, stream>>>(hb, als, ald, row_ptr, col, b2, out, n);
}